// Round 13
// baseline (121.494 us; speedup 1.0000x reference)
//
#include <hip/hip_runtime.h>
#include <cfloat>

#define NFEAT 256
#define BATCH 4096
#define MTOT  16384
#define NSTRIP 32
#define STRIPW 512
#define UMARGIN 0.75f

typedef __attribute__((ext_vector_type(8))) short bf16x8;
typedef __attribute__((ext_vector_type(4))) float f32x4;

#define GP(p)   ((const __attribute__((address_space(1))) void*)(p))
#define LDSP(p) ((__attribute__((address_space(3))) void*)(p))

__device__ __forceinline__ unsigned bf16pack(float a, float b) {
    unsigned ua = __float_as_uint(a), ub = __float_as_uint(b);
    unsigned ra = (ua + 0x7fffu + ((ua >> 16) & 1u)) >> 16;
    unsigned rb = (ub + 0x7fffu + ((ub >> 16) & 1u)) >> 16;
    return ra | (rb << 16);
}

// ---------------------------------------------------------------------------
// Prep A: xb -> bf16 row-major + a2. One wave per row.
// ---------------------------------------------------------------------------
__global__ __launch_bounds__(256) void prep_a_kernel(const float* __restrict__ xb,
                                                     uint2* __restrict__ Abf,
                                                     float* __restrict__ a2) {
    int gid  = blockIdx.x * blockDim.x + threadIdx.x;
    int row  = gid >> 6;
    int lane = gid & 63;
    float4 v = ((const float4*)(xb + (size_t)row * NFEAT))[lane];
    Abf[(size_t)row * 64 + lane] = make_uint2(bf16pack(v.x, v.y), bf16pack(v.z, v.w));
    float s = v.x * v.x + v.y * v.y + v.z * v.z + v.w * v.w;
    #pragma unroll
    for (int off = 32; off > 0; off >>= 1) s += __shfl_down(s, off);
    if (lane == 0) a2[row] = s;
}

// ---------------------------------------------------------------------------
// Prep B: w -> bf16 in MFMA-FRAGMENT order + b2 (identical to rounds 11/12,
// absmax=0 verified). Group g (16 cols), k-slice kk: 1024-B block where byte
// l*16 holds col g*16+(l&15), bf16 elems kk*32+(l>>4)*8 .. +8.
// ---------------------------------------------------------------------------
__global__ __launch_bounds__(256) void prep_b_kernel(const float* __restrict__ w,
                                                     uint4* __restrict__ Bfr,
                                                     float* __restrict__ b2) {
    const int t = threadIdx.x, l = t & 63;
    const int g = blockIdx.x * 4 + (t >> 6);        // 0..1023
    const int col = g * 16 + (l & 15);
    const float4* src = (const float4*)w;           // [16384][64] float4
    float ss = 0.f;
    #pragma unroll
    for (int kk = 0; kk < 8; ++kk) {
        float4 v0 = src[(size_t)col * 64 + kk * 8 + (l >> 4) * 2];
        float4 v1 = src[(size_t)col * 64 + kk * 8 + (l >> 4) * 2 + 1];
        ss += v0.x * v0.x + v0.y * v0.y + v0.z * v0.z + v0.w * v0.w
            + v1.x * v1.x + v1.y * v1.y + v1.z * v1.z + v1.w * v1.w;
        uint4 o;
        o.x = bf16pack(v0.x, v0.y);
        o.y = bf16pack(v0.z, v0.w);
        o.z = bf16pack(v1.x, v1.y);
        o.w = bf16pack(v1.z, v1.w);
        Bfr[(size_t)g * 512 + kk * 64 + l] = o;     // uint4 units (16 B)
    }
    ss += __shfl_xor(ss, 16);
    ss += __shfl_xor(ss, 32);
    if (l < 16) b2[g * 16 + l] = ss;
}

// ---------------------------------------------------------------------------
// Main: 512-ROW blocks — 4x the B-reuse of every prior round. All rounds 3-12
// moved 256 MB of B through the per-CU load path (m13 ceiling ~24.6 B/cyc/CU
// = ~50 us): THE invariant wall. This kernel moves 64 MB unique, LDS-staged.
// Grid 256 (1/CU) x 512 thr (8 waves). Wave tile 64 rows x 16 cols; A panel
// afr[4][8] = 128 VGPR in regs. B staged global->LDS in 64-KB quarters
// (fragment-ordered -> stage AND ds_read both lane-linear: no swizzle, no
// conflicts), 2-buffer ring, vmcnt(8), 2 barriers per quarter (8 total).
// Per-CU per 16-col chunk: MFMA 1242 cyc > LDS 771 -> matrix-pipe-bound.
// min-dist == max-(dot - b2/2); per-lane top-2, 5-bit chunk id in mantissa.
// ---------------------------------------------------------------------------
__global__ __launch_bounds__(512, 1) void som_mfma_kernel(
        const unsigned short* __restrict__ Abf, const unsigned short* __restrict__ Bfr,
        const float* __restrict__ b2, float* __restrict__ part) {
    __shared__ char smem[133120];   // ring 2 x 64 KB | b2 strip 2 KB

    const int t = threadIdx.x, l = t & 63;
    const int wid = t >> 6;
    const int x = blockIdx.x & 7, y = blockIdx.x >> 3;   // y: 0..31
    const int strip = x * 4 + (y & 3);                   // 4 strips per XCD
    const int m0 = (y >> 2) * 512 + wid * 64;            // 64 rows per wave

    // ---- A panel -> 128 VGPRs (frag layout), loaded + pinned ----
    const char* gA = (const char*)Abf + (size_t)(m0 + (l & 15)) * 512 + (l >> 4) * 16;
    bf16x8 afr[4][8];
    #pragma unroll
    for (int m = 0; m < 4; ++m)
        #pragma unroll
        for (int kk = 0; kk < 8; ++kk)
            afr[m][kk] = *(const bf16x8*)(gA + m * 8192 + kk * 64);
    #pragma unroll
    for (int m = 0; m < 4; ++m)
        #pragma unroll
        for (int kk = 0; kk < 8; ++kk)
            asm volatile("" : "+v"(afr[m][kk]));

    // ---- staging: quarter = 128 cols x 512 B = 64 KB = 8 ops/thread ----
    // Bfr is fragment-ordered, so a linear copy gives LDS layout
    // [chunk cc][kk][lane]: both sides lane-linear, conflict-free.
    const char* gBs = (const char*)Bfr + (size_t)strip * 262144 + t * 16;
#define STAGE(p, q) {                                                            \
        _Pragma("unroll")                                                        \
        for (int i_ = 0; i_ < 8; ++i_)                                           \
            __builtin_amdgcn_global_load_lds(GP(gBs + (q) * 65536 + i_ * 8192),  \
                LDSP(smem + (p) * 65536 + i_ * 8192 + t * 16), 16, 0, 0);        \
    }

    // prologue: b2 strip (1 op, 512 thr x 4 B = 2 KB) + quarters 0,1
    __builtin_amdgcn_global_load_lds(GP((const char*)b2 + (size_t)strip * 2048 + t * 4),
                                     LDSP(smem + 131072 + t * 4), 4, 0, 0);
    STAGE(0, 0)
    STAGE(1, 1)

    float r0[4][4], r1[4][4];
    #pragma unroll
    for (int m = 0; m < 4; ++m)
        #pragma unroll
        for (int j = 0; j < 4; ++j) { r0[m][j] = -FLT_MAX; r1[m][j] = -FLT_MAX; }

    for (int q = 0; q < 4; ++q) {
        if (q < 3) asm volatile("s_waitcnt vmcnt(8)" ::: "memory");
        else       asm volatile("s_waitcnt vmcnt(0)" ::: "memory");
        __builtin_amdgcn_s_barrier();
        asm volatile("" ::: "memory");

        const char* buf = smem + ((q & 1) << 16);

        #pragma unroll
        for (int cc = 0; cc < 8; ++cc) {
            const int c = q * 8 + cc;                    // global chunk 0..31
            const float b2c = *(const float*)(smem + 131072 + (c * 16 + (l & 15)) * 4);
            const float bi = -0.5f * b2c;
            f32x4 acc[4];
            #pragma unroll
            for (int m = 0; m < 4; ++m) acc[m] = (f32x4){bi, bi, bi, bi};

            __builtin_amdgcn_s_setprio(1);
            #pragma unroll
            for (int kk = 0; kk < 8; ++kk) {
                bf16x8 bf = *(const bf16x8*)(buf + cc * 8192 + kk * 1024 + l * 16);
                #pragma unroll
                for (int m = 0; m < 4; ++m)
                    acc[m] = __builtin_amdgcn_mfma_f32_16x16x32_bf16(afr[m][kk], bf,
                                                                     acc[m], 0, 0, 0);
            }
            __builtin_amdgcn_s_setprio(0);

            // top-2 fold: 5-bit chunk id in low mantissa bits (3 VALU/elem)
            const unsigned idn = (unsigned)c;
            #pragma unroll
            for (int m = 0; m < 4; ++m)
                #pragma unroll
                for (int j = 0; j < 4; ++j) {
                    float p = __uint_as_float((__float_as_uint(acc[m][j]) & 0xFFFFFFE0u) | idn);
                    float nr1 = __builtin_amdgcn_fmed3f(r0[m][j], r1[m][j], p);
                    r0[m][j] = fmaxf(r0[m][j], p);
                    r1[m][j] = nr1;
                }
        }

        asm volatile("" ::: "memory");
        __builtin_amdgcn_s_barrier();   // all waves done reading buf (q&1)
        asm volatile("" ::: "memory");
        if (q + 2 < 4) STAGE(q & 1, q + 2)
    }

    // ---- per-row merge over 16 lane-cols (repack 9-bit id); direct write.
    //      Each row is owned by exactly one wave: no cross-wave merge. ----
    #pragma unroll
    for (int m = 0; m < 4; ++m)
        #pragma unroll
        for (int j = 0; j < 4; ++j) {
            unsigned u0 = __float_as_uint(r0[m][j]);
            unsigned u1 = __float_as_uint(r1[m][j]);
            u0 = (u0 & 0xFFFFFE00u) | ((u0 & 31u) << 4) | (unsigned)(l & 15);
            u1 = (u1 & 0xFFFFFE00u) | ((u1 & 31u) << 4) | (unsigned)(l & 15);
            float v0 = __uint_as_float(u0), v1 = __uint_as_float(u1);
            #pragma unroll
            for (int off = 1; off < 16; off <<= 1) {
                float o0 = __shfl_xor(v0, off), o1 = __shfl_xor(v1, off);
                float nv1 = fmaxf(fminf(v0, o0), fmaxf(v1, o1));
                v0 = fmaxf(v0, o0);
                v1 = nv1;
            }
            if ((l & 15) == 0) {
                int row = m0 + m * 16 + (l >> 4) * 4 + j;
                ((float2*)part)[(size_t)row * NSTRIP + strip] = make_float2(v0, v1);
            }
        }
#undef STAGE
}

// ---------------------------------------------------------------------------
// Refine: 1 wave per row over 64 packed entries (32 strips x top-2); exact
// fp32+sqrt recompute of candidates within margin; (dist, idx) argmin.
// ---------------------------------------------------------------------------
__global__ __launch_bounds__(256) void refine_kernel(
        const float* __restrict__ xb, const float* __restrict__ w,
        const float* __restrict__ a2, const float* __restrict__ b2,
        const float* __restrict__ part, int* __restrict__ out) {
    const int t = threadIdx.x, l = t & 63;
    const int row = blockIdx.x * 4 + (t >> 6);

    const float v = part[(size_t)row * (NSTRIP * 2) + l];
    float mx = v;
    #pragma unroll
    for (int off = 1; off < 64; off <<= 1) mx = fmaxf(mx, __shfl_xor(mx, off));
    const float cut = mx - UMARGIN;

    unsigned long long key = ~0ull;
    if (v >= cut) {
        unsigned b = __float_as_uint(v);
        int lane4 = b & 15, ch = (b >> 4) & 31, strip = l >> 1;
        int col = strip * STRIPW + ch * 16 + lane4;
        const float4* xr = (const float4*)(xb + (size_t)row * NFEAT);
        const float4* wr = (const float4*)(w + (size_t)col * NFEAT);
        float s0 = 0.f, s1 = 0.f, s2 = 0.f, s3 = 0.f;
        #pragma unroll
        for (int k = 0; k < 16; ++k) {
            float4 x0 = xr[4 * k + 0], w0 = wr[4 * k + 0];
            float4 x1 = xr[4 * k + 1], w1 = wr[4 * k + 1];
            float4 x2 = xr[4 * k + 2], w2 = wr[4 * k + 2];
            float4 x3 = xr[4 * k + 3], w3 = wr[4 * k + 3];
            s0 += x0.x * w0.x + x0.y * w0.y + x0.z * w0.z + x0.w * w0.w;
            s1 += x1.x * w1.x + x1.y * w1.y + x1.z * w1.z + x1.w * w1.w;
            s2 += x2.x * w2.x + x2.y * w2.y + x2.z * w2.z + x2.w * w2.w;
            s3 += x3.x * w3.x + x3.y * w3.y + x3.z * w3.z + x3.w * w3.w;
        }
        float dot = (s0 + s1) + (s2 + s3);
        float dd = a2[row] + b2[col] - 2.f * dot;
        float s = sqrtf(fmaxf(dd, 0.f));
        key = ((unsigned long long)__float_as_uint(s) << 32) | (unsigned)col;
    }
    #pragma unroll
    for (int off = 1; off < 64; off <<= 1) {
        unsigned long long o = __shfl_xor(key, off);
        key = o < key ? o : key;
    }
    if (l == 0) {
        int idx = (int)(key & 0xffffffffu);
        out[2 * row]     = idx >> 7;
        out[2 * row + 1] = idx & 127;
    }
}

extern "C" void kernel_launch(void* const* d_in, const int* in_sizes, int n_in,
                              void* d_out, int out_size, void* d_ws, size_t ws_size,
                              hipStream_t stream) {
    const float* xb = (const float*)d_in[0];   // (4096, 256)
    const float* w  = (const float*)d_in[1];   // (16384, 256)
    int* out = (int*)d_out;

    char* ws = (char*)d_ws;
    unsigned short* Abf = (unsigned short*)ws;                 // 2 MB
    unsigned short* Bfr = (unsigned short*)(ws + (2u << 20));  // 8 MB (frag order)
    float* a2   = (float*)(ws + (10u << 20));                  // 16 KB
    float* b2   = (float*)(ws + (10u << 20) + (64u << 10));    // 64 KB
    float* part = (float*)(ws + (10u << 20) + (128u << 10));   // 1 MB

    prep_a_kernel<<<(BATCH * 64) / 256, 256, 0, stream>>>(xb, (uint2*)Abf, a2);
    prep_b_kernel<<<MTOT / 64, 256, 0, stream>>>(w, (uint4*)Bfr, b2);
    som_mfma_kernel<<<256, 512, 0, stream>>>(Abf, Bfr, b2, part);
    refine_kernel<<<BATCH / 4, 256, 0, stream>>>(xb, w, a2, b2, part, out);
}

// Round 14
// 77.258 us; speedup vs baseline: 1.5726x; 1.5726x over previous
//
#include <hip/hip_runtime.h>
#include <cfloat>

#define NFEAT 256
#define BATCH 4096
#define MTOT  16384
#define NSTRIP 32
#define STRIPW 512
#define NCH 32                // 16-col phases per strip
#define UMARGIN 0.75f

typedef __attribute__((ext_vector_type(8))) short bf16x8;
typedef __attribute__((ext_vector_type(4))) float f32x4;

#define GP(p)   ((const __attribute__((address_space(1))) void*)(p))
#define LDSP(p) ((__attribute__((address_space(3))) void*)(p))

__device__ __forceinline__ unsigned bf16pack(float a, float b) {
    unsigned ua = __float_as_uint(a), ub = __float_as_uint(b);
    unsigned ra = (ua + 0x7fffu + ((ua >> 16) & 1u)) >> 16;
    unsigned rb = (ub + 0x7fffu + ((ub >> 16) & 1u)) >> 16;
    return ra | (rb << 16);
}

// ---------------------------------------------------------------------------
// Prep A: xb -> bf16 row-major + a2. One wave per row.
// ---------------------------------------------------------------------------
__global__ __launch_bounds__(256) void prep_a_kernel(const float* __restrict__ xb,
                                                     uint2* __restrict__ Abf,
                                                     float* __restrict__ a2) {
    int gid  = blockIdx.x * blockDim.x + threadIdx.x;
    int row  = gid >> 6;
    int lane = gid & 63;
    float4 v = ((const float4*)(xb + (size_t)row * NFEAT))[lane];
    Abf[(size_t)row * 64 + lane] = make_uint2(bf16pack(v.x, v.y), bf16pack(v.z, v.w));
    float s = v.x * v.x + v.y * v.y + v.z * v.z + v.w * v.w;
    #pragma unroll
    for (int off = 32; off > 0; off >>= 1) s += __shfl_down(s, off);
    if (lane == 0) a2[row] = s;
}

// ---------------------------------------------------------------------------
// Prep B: w -> bf16 in MFMA-FRAGMENT order + b2 (identical to rounds 11-13,
// absmax=0 verified). Group g (16 cols), k-slice kk: 1024-B block where byte
// l*16 holds col g*16+(l&15), bf16 elems kk*32+(l>>4)*8 .. +8.
// ---------------------------------------------------------------------------
__global__ __launch_bounds__(256) void prep_b_kernel(const float* __restrict__ w,
                                                     uint4* __restrict__ Bfr,
                                                     float* __restrict__ b2) {
    const int t = threadIdx.x, l = t & 63;
    const int g = blockIdx.x * 4 + (t >> 6);        // 0..1023
    const int col = g * 16 + (l & 15);
    const float4* src = (const float4*)w;           // [16384][64] float4
    float ss = 0.f;
    #pragma unroll
    for (int kk = 0; kk < 8; ++kk) {
        float4 v0 = src[(size_t)col * 64 + kk * 8 + (l >> 4) * 2];
        float4 v1 = src[(size_t)col * 64 + kk * 8 + (l >> 4) * 2 + 1];
        ss += v0.x * v0.x + v0.y * v0.y + v0.z * v0.z + v0.w * v0.w
            + v1.x * v1.x + v1.y * v1.y + v1.z * v1.z + v1.w * v1.w;
        uint4 o;
        o.x = bf16pack(v0.x, v0.y);
        o.y = bf16pack(v0.z, v0.w);
        o.z = bf16pack(v1.x, v1.y);
        o.w = bf16pack(v1.z, v1.w);
        Bfr[(size_t)g * 512 + kk * 64 + l] = o;     // uint4 units (16 B)
    }
    ss += __shfl_xor(ss, 16);
    ss += __shfl_xor(ss, 32);
    if (l < 16) b2[g * 16 + l] = ss;
}

// ---------------------------------------------------------------------------
// Main: FINE-PHASE pipeline (T3+T4 port of the verified m201 discipline).
// All rounds 3-12 were coarse 2-phase structures -> the measured ~690 TF
// 2-phase plateau (m233). This kernel: 32 phases of ONE 16-col chunk (8 KB),
// per phase {vmcnt(3) -> barrier -> issue stage(c+4) -> 8 ds_read -> 32 MFMA
// (setprio) -> fold}. Ring 8 x 8 KB: in-flight writes (slots c+1..c+4) are
// disjoint from the read slot (c) -> ONE barrier/phase, vmcnt never drains
// to 0 until the last 4 phases. 512-row blocks: unique B = 64 MB total.
// Grid 256 (1/CU) x 512 thr (8 waves x 64 rows); A panel afr[4][8] pinned;
// launch_bounds(512,2) — (512,1) caused the round-13 scratch spill.
// Bfr fragment-ordered: stage and ds_read both lane-linear, conflict-free.
// min-dist == max-(dot - b2/2); per-lane top-2, 5-bit chunk id in mantissa.
// ---------------------------------------------------------------------------
__global__ __launch_bounds__(512, 2) void som_mfma_kernel(
        const unsigned short* __restrict__ Abf, const unsigned short* __restrict__ Bfr,
        const float* __restrict__ b2, float* __restrict__ part) {
    __shared__ char smem[67584];    // ring 8 x 8 KB = 64 KB | b2 strip 2 KB

    const int t = threadIdx.x, l = t & 63;
    const int wid = t >> 6;
    const int x = blockIdx.x & 7, y = blockIdx.x >> 3;   // y: 0..31
    const int strip = x * 4 + (y & 3);                   // 4 strips per XCD
    const int m0 = (y >> 2) * 512 + wid * 64;            // 64 rows per wave

    // ---- A panel -> 128 regs (frag layout), loaded + pinned ----
    const char* gA = (const char*)Abf + (size_t)(m0 + (l & 15)) * 512 + (l >> 4) * 16;
    bf16x8 afr[4][8];
    #pragma unroll
    for (int m = 0; m < 4; ++m)
        #pragma unroll
        for (int kk = 0; kk < 8; ++kk)
            afr[m][kk] = *(const bf16x8*)(gA + m * 8192 + kk * 64);
    #pragma unroll
    for (int m = 0; m < 4; ++m)
        #pragma unroll
        for (int kk = 0; kk < 8; ++kk)
            asm volatile("" : "+v"(afr[m][kk]));

    // ---- staging: one 16-col chunk = 8 KB = 1 op/thread ----
    const char* gBs = (const char*)Bfr + (size_t)strip * 262144 + t * 16;

    // prologue: b2 strip (1 op) + chunks 0..3 into ring slots 0..3
    __builtin_amdgcn_global_load_lds(GP((const char*)b2 + (size_t)strip * 2048 + t * 4),
                                     LDSP(smem + 65536 + t * 4), 4, 0, 0);
    #pragma unroll
    for (int c = 0; c < 4; ++c)
        __builtin_amdgcn_global_load_lds(GP(gBs + c * 8192),
                                         LDSP(smem + c * 8192 + t * 16), 16, 0, 0);

    float r0[4][4], r1[4][4];
    #pragma unroll
    for (int m = 0; m < 4; ++m)
        #pragma unroll
        for (int j = 0; j < 4; ++j) { r0[m][j] = -FLT_MAX; r1[m][j] = -FLT_MAX; }

    for (int c = 0; c < NCH; ++c) {
        // counted drain: chunk c landed; chunks c+1..c+3 stay in flight
        if (c < NCH - 4) asm volatile("s_waitcnt vmcnt(3)" ::: "memory");
        else             asm volatile("s_waitcnt vmcnt(0)" ::: "memory");
        __builtin_amdgcn_s_barrier();   // cross-wave visibility of chunk c
        asm volatile("" ::: "memory");

        // issue next stage (slot (c+4)&7 — disjoint from read slot c&7)
        if (c + 4 < NCH)
            __builtin_amdgcn_global_load_lds(GP(gBs + (size_t)(c + 4) * 8192),
                LDSP(smem + ((c + 4) & 7) * 8192 + t * 16), 16, 0, 0);

        const float b2c = *(const float*)(smem + 65536 + (c * 16 + (l & 15)) * 4);
        const float bi = -0.5f * b2c;
        f32x4 acc[4];
        #pragma unroll
        for (int m = 0; m < 4; ++m) acc[m] = (f32x4){bi, bi, bi, bi};

        const char* buf = smem + (c & 7) * 8192;
        __builtin_amdgcn_s_setprio(1);
        #pragma unroll
        for (int kk = 0; kk < 8; ++kk) {
            bf16x8 bf = *(const bf16x8*)(buf + kk * 1024 + l * 16);
            #pragma unroll
            for (int m = 0; m < 4; ++m)
                acc[m] = __builtin_amdgcn_mfma_f32_16x16x32_bf16(afr[m][kk], bf,
                                                                 acc[m], 0, 0, 0);
        }
        __builtin_amdgcn_s_setprio(0);

        // top-2 fold: 5-bit chunk id in low mantissa bits (3 VALU/elem)
        const unsigned idn = (unsigned)c;
        #pragma unroll
        for (int m = 0; m < 4; ++m)
            #pragma unroll
            for (int j = 0; j < 4; ++j) {
                float p = __uint_as_float((__float_as_uint(acc[m][j]) & 0xFFFFFFE0u) | idn);
                float nr1 = __builtin_amdgcn_fmed3f(r0[m][j], r1[m][j], p);
                r0[m][j] = fmaxf(r0[m][j], p);
                r1[m][j] = nr1;
            }
    }

    // ---- per-row merge over 16 lane-cols (repack 9-bit id); direct write.
    //      Each row is owned by exactly one wave: no cross-wave merge. ----
    #pragma unroll
    for (int m = 0; m < 4; ++m)
        #pragma unroll
        for (int j = 0; j < 4; ++j) {
            unsigned u0 = __float_as_uint(r0[m][j]);
            unsigned u1 = __float_as_uint(r1[m][j]);
            u0 = (u0 & 0xFFFFFE00u) | ((u0 & 31u) << 4) | (unsigned)(l & 15);
            u1 = (u1 & 0xFFFFFE00u) | ((u1 & 31u) << 4) | (unsigned)(l & 15);
            float v0 = __uint_as_float(u0), v1 = __uint_as_float(u1);
            #pragma unroll
            for (int off = 1; off < 16; off <<= 1) {
                float o0 = __shfl_xor(v0, off), o1 = __shfl_xor(v1, off);
                float nv1 = fmaxf(fminf(v0, o0), fmaxf(v1, o1));
                v0 = fmaxf(v0, o0);
                v1 = nv1;
            }
            if ((l & 15) == 0) {
                int row = m0 + m * 16 + (l >> 4) * 4 + j;
                ((float2*)part)[(size_t)row * NSTRIP + strip] = make_float2(v0, v1);
            }
        }
}

// ---------------------------------------------------------------------------
// Refine: 1 wave per row over 64 packed entries (32 strips x top-2); exact
// fp32+sqrt recompute of candidates within margin; (dist, idx) argmin.
// ---------------------------------------------------------------------------
__global__ __launch_bounds__(256) void refine_kernel(
        const float* __restrict__ xb, const float* __restrict__ w,
        const float* __restrict__ a2, const float* __restrict__ b2,
        const float* __restrict__ part, int* __restrict__ out) {
    const int t = threadIdx.x, l = t & 63;
    const int row = blockIdx.x * 4 + (t >> 6);

    const float v = part[(size_t)row * (NSTRIP * 2) + l];
    float mx = v;
    #pragma unroll
    for (int off = 1; off < 64; off <<= 1) mx = fmaxf(mx, __shfl_xor(mx, off));
    const float cut = mx - UMARGIN;

    unsigned long long key = ~0ull;
    if (v >= cut) {
        unsigned b = __float_as_uint(v);
        int lane4 = b & 15, ch = (b >> 4) & 31, strip = l >> 1;
        int col = strip * STRIPW + ch * 16 + lane4;
        const float4* xr = (const float4*)(xb + (size_t)row * NFEAT);
        const float4* wr = (const float4*)(w + (size_t)col * NFEAT);
        float s0 = 0.f, s1 = 0.f, s2 = 0.f, s3 = 0.f;
        #pragma unroll
        for (int k = 0; k < 16; ++k) {
            float4 x0 = xr[4 * k + 0], w0 = wr[4 * k + 0];
            float4 x1 = xr[4 * k + 1], w1 = wr[4 * k + 1];
            float4 x2 = xr[4 * k + 2], w2 = wr[4 * k + 2];
            float4 x3 = xr[4 * k + 3], w3 = wr[4 * k + 3];
            s0 += x0.x * w0.x + x0.y * w0.y + x0.z * w0.z + x0.w * w0.w;
            s1 += x1.x * w1.x + x1.y * w1.y + x1.z * w1.z + x1.w * w1.w;
            s2 += x2.x * w2.x + x2.y * w2.y + x2.z * w2.z + x2.w * w2.w;
            s3 += x3.x * w3.x + x3.y * w3.y + x3.z * w3.z + x3.w * w3.w;
        }
        float dot = (s0 + s1) + (s2 + s3);
        float dd = a2[row] + b2[col] - 2.f * dot;
        float s = sqrtf(fmaxf(dd, 0.f));
        key = ((unsigned long long)__float_as_uint(s) << 32) | (unsigned)col;
    }
    #pragma unroll
    for (int off = 1; off < 64; off <<= 1) {
        unsigned long long o = __shfl_xor(key, off);
        key = o < key ? o : key;
    }
    if (l == 0) {
        int idx = (int)(key & 0xffffffffu);
        out[2 * row]     = idx >> 7;
        out[2 * row + 1] = idx & 127;
    }
}

extern "C" void kernel_launch(void* const* d_in, const int* in_sizes, int n_in,
                              void* d_out, int out_size, void* d_ws, size_t ws_size,
                              hipStream_t stream) {
    const float* xb = (const float*)d_in[0];   // (4096, 256)
    const float* w  = (const float*)d_in[1];   // (16384, 256)
    int* out = (int*)d_out;

    char* ws = (char*)d_ws;
    unsigned short* Abf = (unsigned short*)ws;                 // 2 MB
    unsigned short* Bfr = (unsigned short*)(ws + (2u << 20));  // 8 MB (frag order)
    float* a2   = (float*)(ws + (10u << 20));                  // 16 KB
    float* b2   = (float*)(ws + (10u << 20) + (64u << 10));    // 64 KB
    float* part = (float*)(ws + (10u << 20) + (128u << 10));   // 1 MB

    prep_a_kernel<<<(BATCH * 64) / 256, 256, 0, stream>>>(xb, (uint2*)Abf, a2);
    prep_b_kernel<<<MTOT / 64, 256, 0, stream>>>(w, (uint4*)Bfr, b2);
    som_mfma_kernel<<<256, 512, 0, stream>>>(Abf, Bfr, b2, part);
    refine_kernel<<<BATCH / 4, 256, 0, stream>>>(xb, w, a2, b2, part, out);
}